// Round 2
// baseline (857.063 us; speedup 1.0000x reference)
//
#include <hip/hip_runtime.h>
#include <math.h>

// Problem constants: N=1024, H=16, D=64, M=64 -> NPAIR = N*H = 16384
#define NPAIR 16384
#define DDIM 64
#define MDIM 64

// Output layout (flat element offsets, return order: V, Si_new, Zi_new, Pi_new)
#define V_OFF   0LL
#define SI_OFF  1048576LL            // NPAIR*MDIM
#define ZI_OFF  68157440LL           // SI_OFF + NPAIR*DDIM*MDIM
#define PI_OFF  69206016LL           // ZI_OFF + NPAIR*DDIM

__global__ __launch_bounds__(256) void rma_kernel(
    const float* __restrict__ query,
    const float* __restrict__ key,
    const float* __restrict__ value,
    const float* __restrict__ Si,
    const float* __restrict__ Zi,
    const float* __restrict__ Pi,
    float* __restrict__ out)
{
    const int pair = blockIdx.x;
    const int tid  = threadIdx.x;

    __shared__ float Qs[DDIM];
    __shared__ float Ks[DDIM];
    __shared__ float Vls[MDIM];
    __shared__ float Vred[16][68];   // pad 68: row stride != multiple of 32 banks
    __shared__ float Zinv;

    const long long vecOff = (long long)pair * DDIM;
    const long long matOff = (long long)pair * (DDIM * MDIM);

    // Stage per-pair vectors + compute normalizer on wave 0
    if (tid < 64) {
        const int d = tid;
        float q  = query[vecOff + d];
        float k  = key[vecOff + d];
        float zi = Zi[vecOff + d];
        // elu(x)+1 == x+1 (x>0) else exp(x)
        float qe = (q > 0.f) ? (q + 1.f) : expf(q);
        float ke = (k > 0.f) ? (k + 1.f) : expf(k);
        float zn = zi + ke;
        Qs[d]  = qe;
        Ks[d]  = ke;
        Vls[d] = value[vecOff + d];        // d doubles as m index here
        out[ZI_OFF + vecOff + d] = zn;     // Zi_new
        float p = qe * zn;
        #pragma unroll
        for (int off = 32; off > 0; off >>= 1)
            p += __shfl_down(p, off, 64);
        if (tid == 0) Zinv = 1.f / (p + 1e-6f);
    }
    __syncthreads();

    // Each thread: 4 rows (d = td + 16r) x 4 cols (m = tm..tm+3), 16B vector IO.
    // Wave lanes 0..63 tile 4 contiguous rows -> 1KB contiguous per instruction.
    const int tm = (tid & 15) << 2;   // m base: 0,4,...,60
    const int td = tid >> 4;          // 0..15

    long long flat[4];
    float4 piu[4], siu[4];
    #pragma unroll
    for (int r = 0; r < 4; ++r) {
        const int d = td + 16 * r;
        flat[r] = matOff + (long long)(d * MDIM + tm);
        piu[r] = *(const float4*)(Pi + flat[r]);
        siu[r] = *(const float4*)(Si + flat[r]);
    }

    float acc[4] = {0.f, 0.f, 0.f, 0.f};
    const float v0 = Vls[tm + 0], v1 = Vls[tm + 1], v2 = Vls[tm + 2], v3 = Vls[tm + 3];
    #pragma unroll
    for (int r = 0; r < 4; ++r) {
        const int d = td + 16 * r;
        const float kd = Ks[d];
        const float qd = Qs[d];
        float4 pn, sn;
        pn.x = 0.9f * piu[r].x - kd * v0;  sn.x = siu[r].x - pn.x;  acc[0] += qd * sn.x;
        pn.y = 0.9f * piu[r].y - kd * v1;  sn.y = siu[r].y - pn.y;  acc[1] += qd * sn.y;
        pn.z = 0.9f * piu[r].z - kd * v2;  sn.z = siu[r].z - pn.z;  acc[2] += qd * sn.z;
        pn.w = 0.9f * piu[r].w - kd * v3;  sn.w = siu[r].w - pn.w;  acc[3] += qd * sn.w;
        *(float4*)(out + PI_OFF + flat[r]) = pn;   // Pi_new
        *(float4*)(out + SI_OFF + flat[r]) = sn;   // Si_new
    }

    // Reduce V over the 16 d-partials per column
    Vred[td][tm + 0] = acc[0];
    Vred[td][tm + 1] = acc[1];
    Vred[td][tm + 2] = acc[2];
    Vred[td][tm + 3] = acc[3];
    __syncthreads();

    if (tid < 64) {
        float s = 0.f;
        #pragma unroll
        for (int t = 0; t < 16; ++t) s += Vred[t][tid];
        out[V_OFF + vecOff + tid] = s * Zinv;   // V
    }
}

extern "C" void kernel_launch(void* const* d_in, const int* in_sizes, int n_in,
                              void* d_out, int out_size, void* d_ws, size_t ws_size,
                              hipStream_t stream)
{
    const float* query = (const float*)d_in[0];
    const float* key   = (const float*)d_in[1];
    const float* value = (const float*)d_in[2];
    const float* Si    = (const float*)d_in[3];
    const float* Zi    = (const float*)d_in[4];
    const float* Pi    = (const float*)d_in[5];
    float* out = (float*)d_out;

    rma_kernel<<<NPAIR, 256, 0, stream>>>(query, key, value, Si, Zi, Pi, out);
}